// Round 5
// baseline (136.028 us; speedup 1.0000x reference)
//
#include <hip/hip_runtime.h>

// CNN self-attention: B=4, C=256, H=W=64 -> N=4096.
// Round 5: two independent barrier domains per CU (256-thr blocks, 32-key
//          chunks, 64KB LDS -> 2 blocks/CU) so softmax VALU of one block
//          overlaps MFMA/LDS of the other; 16-way K swizzle + 4ch/row V
//          layout -> <=2-way bank conflicts (free); counted vmcnt(8) dbuf.
// Workspace: Qh,Kh,Vt f16 (24MB) + Op f16 (32MB) + stats (512KB) + Wh (384KB).

typedef _Float16 f16;
typedef f16 f16x4 __attribute__((ext_vector_type(4)));
typedef f16 f16x8 __attribute__((ext_vector_type(8)));
typedef float f32x16 __attribute__((ext_vector_type(16)));

#define NB 4
#define NC 256
#define NN 4096
#define KVSPLIT 4
#define KRANGE (NN / KVSPLIT)   // 1024 keys per split
#define NCHUNK (KRANGE / 32)    // 32 chunks of 32 keys

typedef const __attribute__((address_space(1))) void* gas_t;
typedef __attribute__((address_space(3))) void* las_t;

__device__ __forceinline__ void load_lds16(const void* g, void* l) {
    // async global->LDS DMA: LDS dest = uniform base + lane*16 (linear)
    __builtin_amdgcn_global_load_lds((gas_t)g, (las_t)l, 16, 0, 0);
}

// ---------------- Kernel 0: W fp32 -> f16 ----------------
__global__ __launch_bounds__(256) void wcvt_kernel(
    const float* __restrict__ Wq, const float* __restrict__ Wk,
    const float* __restrict__ Wv, f16* __restrict__ Wh)
{
    const int idx = blockIdx.x * 256 + threadIdx.x;   // grid = 768 blocks
    const float* s = (idx < 65536) ? Wq : (idx < 131072 ? Wk : Wv);
    Wh[idx] = (f16)s[idx & 65535];
}

// ---------------- Kernel 1: QKV projection via MFMA ----------------
// (unchanged — validated in rounds 2-4)
__global__ __launch_bounds__(256) void qkv_mfma_kernel(
    const float* __restrict__ x, const f16* __restrict__ Wh,
    const float* __restrict__ bq, const float* __restrict__ bk, const float* __restrict__ bv,
    f16* __restrict__ Qh, f16* __restrict__ Kh, f16* __restrict__ Vt)
{
    const int b  = blockIdx.y;
    const int n0 = blockIdx.x * 64;
    const int t  = threadIdx.x;
    const int wv = t >> 6, l = t & 63, ln = l & 31, g = l >> 5;

    __shared__ char xs[64 * 512];   // x^T tile [n][ci], swizzled granules
    __shared__ char st[32768];      // output staging

    {
        const int ci0 = t >> 4;
        const int nq  = (t & 15) * 4;
        for (int it = 0; it < 16; ++it) {
            const int ci = it * 16 + ci0;
            float v4[4];
            *(float4*)v4 = *(const float4*)(x + ((size_t)b * NC + ci) * NN + n0 + nq);
            const int gr = ci >> 3, lo = (ci & 7) * 2;
            #pragma unroll
            for (int j = 0; j < 4; ++j) {
                const int n = nq + j;
                *(f16*)(xs + n * 512 + ((gr ^ (n & 7)) * 16 + lo)) = (f16)v4[j];
            }
        }
    }
    __syncthreads();

    const int c0 = wv * 64;
    for (int m = 0; m < 3; ++m) {
        const f16*  W    = Wh + m * (NC * NC);
        const float* bias = (m == 0) ? bq : (m == 1 ? bk : bv);

        f32x16 acc[2][2];
        #pragma unroll
        for (int i = 0; i < 2; ++i)
            #pragma unroll
            for (int j = 0; j < 2; ++j)
                #pragma unroll
                for (int r = 0; r < 16; ++r) acc[i][j][r] = 0.0f;

        #pragma unroll
        for (int cs = 0; cs < 16; ++cs) {
            f16x8 a0 = *(const f16x8*)(W + (size_t)(c0 + ln) * NC + cs * 16 + 8 * g);
            f16x8 a1 = *(const f16x8*)(W + (size_t)(c0 + 32 + ln) * NC + cs * 16 + 8 * g);
            const int xb = (cs * 32 + g * 16) ^ ((ln & 7) << 4);
            f16x8 b0 = *(const f16x8*)(xs + ln * 512 + xb);
            f16x8 b1 = *(const f16x8*)(xs + (32 + ln) * 512 + xb);
            acc[0][0] = __builtin_amdgcn_mfma_f32_32x32x16_f16(a0, b0, acc[0][0], 0, 0, 0);
            acc[0][1] = __builtin_amdgcn_mfma_f32_32x32x16_f16(a0, b1, acc[0][1], 0, 0, 0);
            acc[1][0] = __builtin_amdgcn_mfma_f32_32x32x16_f16(a1, b0, acc[1][0], 0, 0, 0);
            acc[1][1] = __builtin_amdgcn_mfma_f32_32x32x16_f16(a1, b1, acc[1][1], 0, 0, 0);
        }

        __syncthreads();
        if (m < 2) {
            #pragma unroll
            for (int ct = 0; ct < 2; ++ct)
                #pragma unroll
                for (int nt = 0; nt < 2; ++nt)
                    #pragma unroll
                    for (int q = 0; q < 4; ++q) {
                        const int cb = c0 + ct * 32 + 8 * q + 4 * g;
                        f16x4 pk;
                        #pragma unroll
                        for (int j = 0; j < 4; ++j)
                            pk[j] = (f16)(acc[ct][nt][q * 4 + j] + bias[cb + j]);
                        const int n  = nt * 32 + ln;
                        const int g8 = cb >> 3;
                        *(f16x4*)(st + n * 512 + ((g8 ^ (n & 7)) * 16 + (cb & 7) * 2)) = pk;
                    }
            __syncthreads();
            f16* dst = (m == 0) ? Qh : Kh;
            const int gi  = t & 31;
            const int nb8 = (t >> 5) * 8;
            #pragma unroll
            for (int k = 0; k < 8; ++k) {
                const int n = nb8 + k;
                const uint4 d = *(const uint4*)(st + n * 512 + ((gi ^ (n & 7)) << 4));
                *(uint4*)(dst + ((size_t)b * NN + n0 + n) * NC + gi * 8) = d;
            }
        } else {
            #pragma unroll
            for (int ct = 0; ct < 2; ++ct)
                #pragma unroll
                for (int nt = 0; nt < 2; ++nt) {
                    const int n  = nt * 32 + ln;
                    const int pn = (n & ~15) | (n & 3) | ((n & 8) >> 1) | ((n & 4) << 1);
                    #pragma unroll
                    for (int r = 0; r < 16; ++r) {
                        const int c = c0 + ct * 32 + (r & 3) + 8 * (r >> 2) + 4 * g;
                        *(f16*)(st + c * 128 + ((pn * 2) ^ ((c & 7) << 4))) =
                            (f16)(acc[ct][nt][r] + bias[c]);
                    }
                }
            __syncthreads();
            #pragma unroll
            for (int ci = 0; ci < 8; ++ci) {
                const int c = ci * 32 + (t >> 3);
                const int s = t & 7;
                const uint4 d = *(const uint4*)(st + c * 128 + ((s ^ (c & 7)) << 4));
                *(uint4*)(Vt + ((size_t)b * NC + c) * NN + n0 + s * 8) = d;
            }
        }
    }
}

// ---------------- Kernel 2: MFMA flash attention ----------------
// 512 blocks x 256 threads = 2 blocks/CU (independent barrier domains),
// 64KB LDS/block: K dbuf [32 rows x 512B] ^(row&15) granule swizzle,
//                 V dbuf [64 rows x 256B] = 4 ch/row, ^(R&3) granule swizzle.
// Per chunk: issue next chunk's 8 DMA -> vmcnt(8) -> s_barrier -> compute
//            -> s_barrier. No vmcnt(0) drain in the main loop.
__global__ __launch_bounds__(256, 2) void flash_mfma_kernel(
    const f16* __restrict__ Qh, const f16* __restrict__ Kh, const f16* __restrict__ Vt,
    f16* __restrict__ Op, float* __restrict__ Mst, float* __restrict__ Lst)
{
    const int t  = threadIdx.x;
    const int wv = t >> 6;         // 0..3
    const int l  = t & 63;
    const int ln = l & 31;
    const int g  = l >> 5;

    // XCD swizzle: 512 blocks, flat%8 = XCD; 2 (b,split) streams per XCD,
    // 32 q-tile blocks per stream stay on one XCD for KV L2 reuse.
    const int flat  = blockIdx.x;        // 0..511
    const int xcd   = flat & 7;
    const int idx   = flat >> 3;         // 0..63
    const int bs    = xcd * 2 + (idx & 1);   // 0..15
    const int qt    = idx >> 1;          // 0..31
    const int b     = bs >> 2;
    const int split = bs & 3;
    const int qrow  = qt * 128 + wv * 32 + ln;

    __shared__ char ldsK[2 * 16384];   // [buf][32 key-rows x 512B]
    __shared__ char ldsV[2 * 16384];   // [buf][64 rows x 256B] (4 ch/row)

    // ---- Q fragments (register-resident) ----
    f16x8 qf[16];
    {
        const f16* Qb = Qh + ((size_t)b * NN + qrow) * NC;
        #pragma unroll
        for (int cs = 0; cs < 16; ++cs)
            qf[cs] = *(const f16x8*)(Qb + cs * 16 + 8 * g);
    }

    f32x16 o[8];
    #pragma unroll
    for (int ct = 0; ct < 8; ++ct)
        #pragma unroll
        for (int r = 0; r < 16; ++r) o[ct][r] = 0.0f;

    float mrun = -1e30f, lrun = 0.0f;
    const int key_base = split * KRANGE;
    const f16* KhB = Kh + (size_t)b * NN * NC;
    const f16* VtB = Vt + (size_t)b * NC * NN;

    // 8 DMA instrs / wave / chunk (1KB each):
    //  K: instr r2=wv*4+j covers key-rows 2r2,2r2+1; lane: row=2r2+(l>>5),
    //     granule u=(l&31)^(row&15)  [16-way spread]
    //  V: instr i=wv*4+j covers rows 4i..4i+3; lane: R=4i+(l>>4),
    //     c=4R+((l&15)>>2), kg=(l&3)^(R&3)
#define DMA(CH, BUF) do {                                                            \
        const int key0_ = key_base + (CH) * 32;                                      \
        _Pragma("unroll")                                                            \
        for (int j = 0; j < 4; ++j) {                                                \
            const int r2  = wv * 4 + j;                                              \
            const int row = r2 * 2 + (l >> 5);                                       \
            const int u   = (l & 31) ^ (row & 15);                                   \
            load_lds16(KhB + (size_t)(key0_ + row) * NC + u * 8,                     \
                       ldsK + (BUF) * 16384 + r2 * 1024);                            \
        }                                                                            \
        _Pragma("unroll")                                                            \
        for (int j = 0; j < 4; ++j) {                                                \
            const int i  = wv * 4 + j;                                               \
            const int R  = i * 4 + (l >> 4);                                         \
            const int c  = R * 4 + ((l & 15) >> 2);                                  \
            const int kg = (l & 3) ^ (R & 3);                                        \
            load_lds16(VtB + (size_t)c * NN + key0_ + kg * 8,                        \
                       ldsV + (BUF) * 16384 + i * 1024);                             \
        }                                                                            \
    } while (0)

    DMA(0, 0);

    for (int ch = 0; ch < NCHUNK; ++ch) {
        const int cb = ch & 1;
        if (ch + 1 < NCHUNK) {
            DMA(ch + 1, cb ^ 1);
            asm volatile("s_waitcnt vmcnt(8)" ::: "memory");   // this chunk landed
        } else {
            asm volatile("s_waitcnt vmcnt(0)" ::: "memory");
        }
        __builtin_amdgcn_s_barrier();   // all waves' DMA landed

        const char* K0 = ldsK + cb * 16384;
        const char* V0 = ldsV + cb * 16384;

        // ---- S^T = K . Q^T (32 keys x 32 queries) ----
        f32x16 s0;
        #pragma unroll
        for (int r = 0; r < 16; ++r) s0[r] = 0.0f;
        __builtin_amdgcn_s_setprio(1);
        #pragma unroll
        for (int cs = 0; cs < 16; ++cs) {
            const int col = ((cs * 2 + g) ^ (ln & 15)) * 16;
            f16x8 a0 = *(const f16x8*)(K0 + ln * 512 + col);
            s0 = __builtin_amdgcn_mfma_f32_32x32x16_f16(a0, qf[cs], s0, 0, 0, 0);
        }
        __builtin_amdgcn_s_setprio(0);

        // ---- online softmax with defer-rescale (T13, THR=8) ----
        float mt = s0[0];
        #pragma unroll
        for (int r = 1; r < 16; ++r) mt = fmaxf(mt, s0[r]);
        mt = fmaxf(mt, __shfl_xor(mt, 32));
        if (!__all(mt <= mrun + 8.0f)) {
            const float mnew  = fmaxf(mrun, mt);
            const float alpha = __expf(mrun - mnew);
            #pragma unroll
            for (int ct = 0; ct < 8; ++ct)
                #pragma unroll
                for (int r = 0; r < 16; ++r) o[ct][r] *= alpha;
            lrun *= alpha;
            mrun  = mnew;
        }

        float ps = 0.0f;
        f16x8 pf[2];   // S^T D-regs map 1:1 onto PV B-frag layout
        #pragma unroll
        for (int r = 0; r < 16; ++r) {
            const float e0 = __expf(s0[r] - mrun);
            ps += e0;
            pf[r >> 3][r & 7] = (f16)e0;
        }
        ps += __shfl_xor(ps, 32);
        lrun += ps;

        // ---- O^T += V^T . P^T ----
        __builtin_amdgcn_s_setprio(1);
        #pragma unroll
        for (int ct = 0; ct < 8; ++ct) {
            const int c    = ct * 32 + ln;
            const int base = (c >> 2) * 256 + (c & 3) * 64;
            const int rsw  = (c >> 2) & 3;
            #pragma unroll
            for (int s = 0; s < 2; ++s) {
                f16x8 va = *(const f16x8*)(V0 + base + (((s * 2 + g) ^ rsw) * 16));
                o[ct] = __builtin_amdgcn_mfma_f32_32x32x16_f16(va, pf[s], o[ct], 0, 0, 0);
            }
        }
        __builtin_amdgcn_s_setprio(0);

        __builtin_amdgcn_s_barrier();   // reads done -> next iter may overwrite buf
    }
#undef DMA

    // ---- epilogue: normalized partial (f16) + stats ----
    const float invl = 1.0f / lrun;
    #pragma unroll
    for (int ct = 0; ct < 8; ++ct)
        #pragma unroll
        for (int r = 0; r < 16; ++r) {
            const int c = ct * 32 + (r & 3) + 8 * (r >> 2) + 4 * g;
            Op[((size_t)(split * NB + b) * NC + c) * NN + qrow] = (f16)(o[ct][r] * invl);
        }
    if (g == 0) {
        Mst[(split * NB + b) * NN + qrow] = mrun;
        Lst[(split * NB + b) * NN + qrow] = lrun;
    }
}

// ---------------- Kernel 3: combine kv-split partials ----------------
__global__ __launch_bounds__(256) void combine_kernel(
    const f16* __restrict__ Op, const float* __restrict__ Mst, const float* __restrict__ Lst,
    float* __restrict__ out)
{
    const int t = threadIdx.x;
    const int b = blockIdx.y;
    const int n = blockIdx.x * 64 + (t & 63);

    float w[KVSPLIT];
    float mm = -1e30f;
    #pragma unroll
    for (int s = 0; s < KVSPLIT; ++s) {
        w[s] = Mst[(s * NB + b) * NN + n];
        mm = fmaxf(mm, w[s]);
    }
    float tot = 0.0f;
    #pragma unroll
    for (int s = 0; s < KVSPLIT; ++s) {
        w[s] = __expf(w[s] - mm) * Lst[(s * NB + b) * NN + n];
        tot += w[s];
    }
    const float inv = 1.0f / tot;
    #pragma unroll
    for (int s = 0; s < KVSPLIT; ++s) w[s] *= inv;

    for (int c = (t >> 6); c < NC; c += 4) {
        float acc = 0.0f;
        #pragma unroll
        for (int s = 0; s < KVSPLIT; ++s)
            acc += w[s] * (float)Op[((size_t)(s * NB + b) * NC + c) * NN + n];
        out[((size_t)b * NC + c) * NN + n] = acc;
    }
}

extern "C" void kernel_launch(void* const* d_in, const int* in_sizes, int n_in,
                              void* d_out, int out_size, void* d_ws, size_t ws_size,
                              hipStream_t stream)
{
    const float* x  = (const float*)d_in[0];
    const float* Wq = (const float*)d_in[1];
    const float* Wk = (const float*)d_in[2];
    const float* Wv = (const float*)d_in[3];
    const float* bq = (const float*)d_in[4];
    const float* bk = (const float*)d_in[5];
    const float* bv = (const float*)d_in[6];
    float* out = (float*)d_out;

    // Workspace layout (~57 MB)
    f16* Qh = (f16*)d_ws;                                       // 8 MB
    f16* Kh = Qh + (size_t)NB * NN * NC;                        // 8 MB
    f16* Vt = Kh + (size_t)NB * NN * NC;                        // 8 MB
    f16* Op = Vt + (size_t)NB * NN * NC;                        // 32 MB
    float* Mst = (float*)(Op + (size_t)KVSPLIT * NB * NC * NN); // 256 KB
    float* Lst = Mst + (size_t)KVSPLIT * NB * NN;               // 256 KB
    f16*  Wh  = (f16*)(Lst + (size_t)KVSPLIT * NB * NN);        // 384 KB

    wcvt_kernel<<<768, 256, 0, stream>>>(Wq, Wk, Wv, Wh);
    qkv_mfma_kernel<<<dim3(NN / 64, NB), 256, 0, stream>>>(
        x, Wh, bq, bk, bv, Qh, Kh, Vt);
    flash_mfma_kernel<<<512, 256, 0, stream>>>(Qh, Kh, Vt, Op, Mst, Lst);
    combine_kernel<<<dim3(NN / 64, NB), 256, 0, stream>>>(Op, Mst, Lst, out);
}